// Round 1
// baseline (225.150 us; speedup 1.0000x reference)
//
#include <hip/hip_runtime.h>

// out[n, mu, mup] = sum over (m1,m2) in T(mu), (m1p,m2p) in T(mup) of
//   mult[p*61+q] * X1[n, m1, m1p] * X2[n, m2, m2p]
// where T(mu) = {(m1,m2): m1+m2 == mu+4}, pairs enumerated mu-major then m1
// ascending (61 valid pairs), and mult is the flattened outer product of CG
// coefficients in exactly that pair order (verified against reference
// _precompute loop structure: t = p*61 + q).
//
// Strategy (round 1 baseline): one thread per batch element. Index structure
// hardcoded at compile time (it is a pure function of L1=L2=LAMBD=4); only
// mult is read at runtime, at fully-constant offsets -> uniform -> s_load
// (scalar pipe), so the inner loop is 2 VALU ops/term (v_mul + v_fmac w/ SGPR
// weight). Per-thread contiguous global loads; wave span 20.7KB/array is
// L1-resident so HBM sees each byte once.

namespace {

struct PTab {
  int v[9][9];
  constexpr PTab() : v{} {
    int idx = 0;
    for (int mu = 0; mu < 9; ++mu)
      for (int m1 = 0; m1 < 9; ++m1) {
        int m2 = mu + 4 - m1;
        if (m2 >= 0 && m2 < 9) v[m1][m2] = idx++;
      }
  }
};
constexpr PTab PT{};

}  // namespace

__global__ __launch_bounds__(64, 1)
void wigner_combine_kernel(const float* __restrict__ X1,
                           const float* __restrict__ X2,
                           const float* __restrict__ mult,
                           float* __restrict__ out, int N) {
  const int n = blockIdx.x * 64 + threadIdx.x;
  if (n >= N) return;

  const float* __restrict__ x1p = X1 + (long)n * 81;
  const float* __restrict__ x2p = X2 + (long)n * 81;

  // X2 fully register-resident (81 VGPRs).
  float x2v[81];
#pragma unroll
  for (int c = 0; c < 81; ++c) x2v[c] = x2p[c];

  float acc[81];
#pragma unroll
  for (int c = 0; c < 81; ++c) acc[c] = 0.0f;

#pragma unroll
  for (int m1 = 0; m1 < 9; ++m1) {
    // Stream X1 one row at a time (9 VGPRs).
    float x1r[9];
#pragma unroll
    for (int j = 0; j < 9; ++j) x1r[j] = x1p[m1 * 9 + j];

#pragma unroll
    for (int m2 = 0; m2 < 9; ++m2) {
      const int mu = m1 + m2 - 4;
      if (mu < 0 || mu > 8) continue;
      const int p = PT.v[m1][m2];

#pragma unroll
      for (int m1p = 0; m1p < 9; ++m1p) {
        const float t = x1r[m1p];
#pragma unroll
        for (int m2p = 0; m2p < 9; ++m2p) {
          const int mup = m1p + m2p - 4;
          if (mup < 0 || mup > 8) continue;
          const int q = PT.v[m1p][m2p];
          // Uniform load at compile-time-constant offset -> s_load.
          const float w = mult[p * 61 + q];
          acc[mu * 9 + mup] += w * (t * x2v[m2 * 9 + m2p]);
        }
      }
    }
  }

  float* __restrict__ op = out + (long)n * 81;
#pragma unroll
  for (int c = 0; c < 81; ++c) op[c] = acc[c];
}

extern "C" void kernel_launch(void* const* d_in, const int* in_sizes, int n_in,
                              void* d_out, int out_size, void* d_ws, size_t ws_size,
                              hipStream_t stream) {
  const float* X1 = (const float*)d_in[0];
  const float* X2 = (const float*)d_in[1];
  // d_in[2..5] = m1, m1p, m2, m2p (index structure hardcoded; unused)
  const float* mult = (const float*)d_in[6];
  // d_in[7] = mu_both (hardcoded; unused)
  float* out = (float*)d_out;

  const int N = in_sizes[0] / 81;
  const int blocks = (N + 63) / 64;
  wigner_combine_kernel<<<blocks, 64, 0, stream>>>(X1, X2, mult, out, N);
}

// Round 2
// 191.030 us; speedup vs baseline: 1.1786x; 1.1786x over previous
//
#include <hip/hip_runtime.h>

// out[n, mu, mup] = sum_{(m1,m2)∈T(mu)} sum_{(m1p,m2p)∈T(mup)}
//     mult[p*61+q] * X1[n,m1,m1p] * X2[n,m2,m2p],   T(mu)={m1+m2==mu+4}
// with p,q the mu-major pair enumeration (61 pairs), t = p*61+q (verified vs
// reference _precompute()).
//
// R2 strategy: one thread per (n, mu) pair.
//  - R1 failed on spills (VGPR=256, WRITE 90MB vs 16.2 ideal) and grid-limited
//    occupancy (782 waves total). Splitting by mu gives 9x the waves (~6.9/SIMD)
//    and cuts live state to acc[9]+x1r[9]+x2r[9] (~50 VGPR, no spills).
//  - mu = blockIdx.y is wave-uniform -> template-specialized bodies, fully
//    unrolled, weight loads at compile-time offsets -> scalar loads (K$).
//  - Row re-reads across mu hit L2/L3 (inputs only 32.4 MB total).

namespace {

struct PTab {
  int v[9][9];
  constexpr PTab() : v{} {
    int idx = 0;
    for (int mu = 0; mu < 9; ++mu)
      for (int m1 = 0; m1 < 9; ++m1) {
        int m2 = mu + 4 - m1;
        if (m2 >= 0 && m2 < 9) v[m1][m2] = idx++;
      }
  }
};
constexpr PTab PT{};

}  // namespace

template <int MU>
__device__ __forceinline__ void do_mu(const float* __restrict__ x1p,
                                      const float* __restrict__ x2p,
                                      const float* __restrict__ mult,
                                      float* __restrict__ op) {
  float acc[9];
#pragma unroll
  for (int j = 0; j < 9; ++j) acc[j] = 0.0f;

#pragma unroll
  for (int m1 = 0; m1 < 9; ++m1) {
    const int m2 = MU + 4 - m1;           // compile-time per unrolled iter
    if (m2 < 0 || m2 > 8) continue;
    const int p = PT.v[m1][m2];

    float x1r[9], x2r[9];
#pragma unroll
    for (int j = 0; j < 9; ++j) x1r[j] = x1p[m1 * 9 + j];
#pragma unroll
    for (int j = 0; j < 9; ++j) x2r[j] = x2p[m2 * 9 + j];

#pragma unroll
    for (int m1p = 0; m1p < 9; ++m1p) {
#pragma unroll
      for (int m2p = 0; m2p < 9; ++m2p) {
        const int mup = m1p + m2p - 4;
        if (mup < 0 || mup > 8) continue;
        const int q = PT.v[m1p][m2p];
        const float w = mult[p * 61 + q];  // constant offset -> s_load
        acc[mup] = fmaf(w, x1r[m1p] * x2r[m2p], acc[mup]);
      }
    }
  }

#pragma unroll
  for (int j = 0; j < 9; ++j) op[j] = acc[j];
}

__global__ __launch_bounds__(64)
void wigner_combine_kernel(const float* __restrict__ X1,
                           const float* __restrict__ X2,
                           const float* __restrict__ mult,
                           float* __restrict__ out, int N) {
  const int n = blockIdx.x * 64 + threadIdx.x;
  if (n >= N) return;

  const float* x1p = X1 + (long)n * 81;
  const float* x2p = X2 + (long)n * 81;
  float* op = out + (long)n * 81 + blockIdx.y * 9;

  switch (blockIdx.y) {
    case 0: do_mu<0>(x1p, x2p, mult, op); break;
    case 1: do_mu<1>(x1p, x2p, mult, op); break;
    case 2: do_mu<2>(x1p, x2p, mult, op); break;
    case 3: do_mu<3>(x1p, x2p, mult, op); break;
    case 4: do_mu<4>(x1p, x2p, mult, op); break;
    case 5: do_mu<5>(x1p, x2p, mult, op); break;
    case 6: do_mu<6>(x1p, x2p, mult, op); break;
    case 7: do_mu<7>(x1p, x2p, mult, op); break;
    case 8: do_mu<8>(x1p, x2p, mult, op); break;
  }
}

extern "C" void kernel_launch(void* const* d_in, const int* in_sizes, int n_in,
                              void* d_out, int out_size, void* d_ws, size_t ws_size,
                              hipStream_t stream) {
  const float* X1 = (const float*)d_in[0];
  const float* X2 = (const float*)d_in[1];
  const float* mult = (const float*)d_in[6];
  float* out = (float*)d_out;

  const int N = in_sizes[0] / 81;
  dim3 grid((N + 63) / 64, 9);
  wigner_combine_kernel<<<grid, 64, 0, stream>>>(X1, X2, mult, out, N);
}

// Round 4
// 109.720 us; speedup vs baseline: 2.0520x; 1.7411x over previous
//
#include <hip/hip_runtime.h>

// out[n, mu, mup] = sum_{(m1,m2)∈T(mu)} sum_{(m1p,m2p)∈T(mup)}
//     mult[p*61+q] * X1[n,m1,m1p] * X2[n,m2,m2p],   T(mu)={m1+m2==mu+4}
// p,q = mu-major pair enumeration (61 pairs), weight index t = p*61+q.
//
// R3 (resubmit after broker timeout): R2 had FETCH=326MB (=9x input: each
// mu-block re-fetched X1/X2 across XCDs). Fix: one block = 64 n x ALL 9 mu
// (576 thr, wave=mu, lane=n-local), inputs staged to LDS once -> HBM sees
// each byte once (48.6 MB total).
//  - LDS component-major [c][n] pitch 65 -> conflict-free reads & transpose.
//  - mu scalarized via readfirstlane -> weight loads are wave-uniform s_loads.
//  - inner 61-term loop unrolled w/ compile-time (m1p,m2p,mup) tables.
//  - output transposed back through LDS (reuse x1 buf) -> coalesced stores.

namespace {

// pairs per mu: [5,6,7,8,9,8,7,6,5]; prefix = first pair index of each mu
__constant__ __device__ const int kPrefix[9] = {0, 5, 11, 18, 26, 35, 43, 50, 56};

// q-enumeration tables (mup-major, m1p ascending) — compile-time
struct QTab {
  int m1p[61];
  int m2p[61];
  int mup[61];
  constexpr QTab() : m1p{}, m2p{}, mup{} {
    int idx = 0;
    for (int mu = 0; mu < 9; ++mu)
      for (int a = 0; a < 9; ++a) {
        int b = mu + 4 - a;
        if (b >= 0 && b < 9) {
          m1p[idx] = a; m2p[idx] = b; mup[idx] = mu; ++idx;
        }
      }
  }
};
constexpr QTab QT{};

}  // namespace

#define NB 64           // n per block
#define NT 576          // threads = 9 waves
#define PITCH 65        // LDS n-pitch (odd -> bank-conflict-free)
#define ELEMS (NB * 81) // 5184 floats per array per block

__global__ __launch_bounds__(NT, 6)
void wigner_combine_kernel(const float* __restrict__ X1,
                           const float* __restrict__ X2,
                           const float* __restrict__ mult,
                           float* __restrict__ out, int N) {
  __shared__ float x1s[81 * PITCH];
  __shared__ float x2s[81 * PITCH];

  const int t = threadIdx.x;
  const int base = blockIdx.x * ELEMS;
  const int total = N * 81;

  // ---- stage: coalesced global loads, transposed LDS writes ----
#pragma unroll
  for (int j = 0; j < 9; ++j) {
    const int e = t + j * NT;        // 0..5183
    const int n = e / 81;            // magic-div
    const int c = e - n * 81;
    const int ge = base + e;
    float v1 = 0.0f, v2 = 0.0f;
    if (ge < total) { v1 = X1[ge]; v2 = X2[ge]; }
    x1s[c * PITCH + n] = v1;
    x2s[c * PITCH + n] = v2;
  }
  __syncthreads();

  // ---- compute: wave = mu, lane = local n ----
  const int mu = __builtin_amdgcn_readfirstlane(t >> 6);  // scalar
  const int lane = t & 63;

  float acc[9];
#pragma unroll
  for (int j = 0; j < 9; ++j) acc[j] = 0.0f;

  const int m1lo = (mu - 4 > 0) ? mu - 4 : 0;
  const int m1hi = (mu + 4 < 8) ? mu + 4 : 8;
  int p = kPrefix[mu];

  for (int m1 = m1lo; m1 <= m1hi; ++m1, ++p) {
    const int m2 = mu + 4 - m1;

    float x1r[9], x2r[9];
#pragma unroll
    for (int j = 0; j < 9; ++j) x1r[j] = x1s[(m1 * 9 + j) * PITCH + lane];
#pragma unroll
    for (int j = 0; j < 9; ++j) x2r[j] = x2s[(m2 * 9 + j) * PITCH + lane];

    const float* __restrict__ wrow = mult + p * 61;  // scalar base -> s_loads
#pragma unroll
    for (int q = 0; q < 61; ++q) {
      acc[QT.mup[q]] = fmaf(wrow[q], x1r[QT.m1p[q]] * x2r[QT.m2p[q]],
                            acc[QT.mup[q]]);
    }
  }

  // ---- transpose result through LDS (reuse x1s), coalesced stores ----
  __syncthreads();
#pragma unroll
  for (int j = 0; j < 9; ++j) x1s[(mu * 9 + j) * PITCH + lane] = acc[j];
  __syncthreads();

#pragma unroll
  for (int j = 0; j < 9; ++j) {
    const int e = t + j * NT;
    const int n = e / 81;
    const int c = e - n * 81;
    const int ge = base + e;
    if (ge < total) out[ge] = x1s[c * PITCH + n];
  }
}

extern "C" void kernel_launch(void* const* d_in, const int* in_sizes, int n_in,
                              void* d_out, int out_size, void* d_ws, size_t ws_size,
                              hipStream_t stream) {
  const float* X1 = (const float*)d_in[0];
  const float* X2 = (const float*)d_in[1];
  const float* mult = (const float*)d_in[6];
  float* out = (float*)d_out;

  const int N = in_sizes[0] / 81;
  const int blocks = (N + NB - 1) / NB;
  wigner_combine_kernel<<<blocks, NT, 0, stream>>>(X1, X2, mult, out, N);
}